// Round 4
// baseline (161.189 us; speedup 1.0000x reference)
//
#include <hip/hip_runtime.h>

typedef _Float16 half8  __attribute__((ext_vector_type(8)));
typedef float    f32x4  __attribute__((ext_vector_type(4)));

#define B_ 16
#define C_ 256
#define N_ 4096
#define TAU 0.02f

// ---------- top-2 merge (desc order, first-index wins on equal value) ----------
__device__ __forceinline__ void top2_merge(float& v1, int& i1, float& v2, int& i2,
                                           float w1, int j1, float w2, int j2) {
    bool bwin = (w1 > v1) || (w1 == v1 && j1 < i1);
    float t1 = bwin ? w1 : v1; int ti1 = bwin ? j1 : i1;
    float lv = bwin ? v1 : w1; int li  = bwin ? i1 : j1;   // loser's top1
    float wv = bwin ? w2 : v2; int wi  = bwin ? i2 : j2;   // winner's top2
    bool c2 = (lv > wv) || (lv == wv && li < wi);
    v2 = c2 ? lv : wv; i2 = c2 ? li : wi;
    v1 = t1; i1 = ti1;
}

// ---------- prep: W' = 16*W -> f16 hi/lo, stored A-fragment-major ----------
// f16 index: ((cb*8+s)*64 + l)*8 + j ;  c = cb*16+(l&15), i = s*32+(l>>4)*8+j
__global__ void prep_w(const float* __restrict__ W,
                       _Float16* __restrict__ WfH, _Float16* __restrict__ WfL) {
    int t = blockIdx.x * 256 + threadIdx.x;  // 0..8191
    int l = t & 63, g = t >> 6;
    int s = g & 7, cb = g >> 3;              // cb 0..15
    int c = cb * 16 + (l & 15);
    int i0 = s * 32 + (l >> 4) * 8;
    int base = ((cb * 8 + s) * 64 + l) * 8;
#pragma unroll
    for (int j = 0; j < 8; ++j) {
        float w = 16.0f * W[c * C_ + i0 + j];   // x16 keeps W_lo out of f16-denormal range
        _Float16 h  = (_Float16)w;
        _Float16 lo = (_Float16)(w - (float)h);
        WfH[base + j] = h;
        WfL[base + j] = lo;
    }
}

// ---------- main: d = W'@xh via 2-pass f16 MFMA (W hi+lo, x hi-only) ----------
// grid: 16 b * 128 n-chunks (32 n); 512 threads = 8 waves.
// wave wid: nw = wid&1 (16-n half), cw = wid>>1 (64-c range). acc = 48 regs.
__global__ __launch_bounds__(512, 4) void vn_main(
    const float* __restrict__ x,
    const _Float16* __restrict__ WfH, const _Float16* __restrict__ WfL,
    float4* __restrict__ btop)
{
    __shared__ __align__(16) _Float16 XH[2][3072];   // [buf][(k*2+nf)*64 + l]*8 + j
    __shared__ float4 btmp[C_];                      // nw0 -> nw1 top-2 handoff

    const int tid  = threadIdx.x;
    const int lane = tid & 63;
    const int wid  = tid >> 6;           // 0..7
    const int nw   = wid & 1;            // n-half
    const int cw   = wid >> 1;           // c-quarter
    const int b    = blockIdx.x >> 7;
    const int nb   = blockIdx.x & 127;
    const int n0   = nb << 5;

    const float* xb = x + ((size_t)(b * 768) << 12);

    f32x4 acc[3][4];
    const f32x4 zero = {0.f, 0.f, 0.f, 0.f};
#pragma unroll
    for (int k = 0; k < 3; ++k)
#pragma unroll
        for (int cf = 0; cf < 4; ++cf) acc[k][cf] = zero;

    // staging map: thread loads i_loc = grp (=tid>>4), k = q, n-pair 2*np
    const int np  = tid & 15;
    const int grp = tid >> 4;            // 0..31

    float2 v[3];
    half8 ah[4], al[4];

#define LOADX(S)                                                                   \
    do {                                                                           \
        _Pragma("unroll") for (int q = 0; q < 3; ++q)                              \
            v[q] = *(const float2*)(xb +                                           \
                (((32 * (S) + grp) * 3 + q) << 12) + n0 + 2 * np);                 \
    } while (0)

#define WRITEX(BUF)                                                               \
    do {                                                                          \
        _Pragma("unroll") for (int q = 0; q < 3; ++q) {                           \
            _Float16 h0 = (_Float16)v[q].x;                                       \
            _Float16 h1 = (_Float16)v[q].y;                                       \
            int nf  = np >> 3;                                                    \
            int la  = ((grp >> 3) << 4) | ((2 * np) & 15);                        \
            int idx = ((q * 2 + nf) * 64 + la) * 8 + (grp & 7);                   \
            XH[BUF][idx]     = h0;                                                \
            XH[BUF][idx + 8] = h1;                                                \
        }                                                                         \
    } while (0)

#define LOADW(S)                                                                  \
    do {                                                                          \
        _Pragma("unroll") for (int cf = 0; cf < 4; ++cf) {                        \
            int cb  = (cw << 2) + cf;                                             \
            int off = (((cb << 3) + (S)) * 64 + lane) * 8;                        \
            ah[cf] = *(const half8*)(WfH + off);                                  \
            al[cf] = *(const half8*)(WfL + off);                                  \
        }                                                                         \
    } while (0)

#define MFMA_STEP(BUF)                                                            \
    do {                                                                          \
        _Pragma("unroll") for (int k = 0; k < 3; ++k) {                           \
            const half8 bh = *(const half8*)(&XH[BUF][((k * 2 + nw) * 64 + lane) * 8]); \
            _Pragma("unroll") for (int cf = 0; cf < 4; ++cf) {                    \
                acc[k][cf] = __builtin_amdgcn_mfma_f32_16x16x32_f16(ah[cf], bh, acc[k][cf], 0, 0, 0); \
                acc[k][cf] = __builtin_amdgcn_mfma_f32_16x16x32_f16(al[cf], bh, acc[k][cf], 0, 0, 0); \
            }                                                                     \
        }                                                                         \
    } while (0)

    // prologue
    LOADX(0);
    LOADW(0);
    WRITEX(0);

#pragma unroll
    for (int s = 0; s < 8; ++s) {
        const int cur = s & 1;
        __syncthreads();                  // buf[cur] complete
        if (s < 7) LOADX(s + 1);          // HBM loads in flight across MFMA
        MFMA_STEP(cur);
        if (s < 7) { LOADW(s + 1); WRITEX(cur ^ 1); }
    }

    // epilogue: dp = sum_k x*d / 16; top-2 over wave's 16 n; merge halves via LDS
    const int t16   = lane & 15;
    const int g     = lane >> 4;
    const int nbase = n0 + (nw << 4);
#pragma unroll
    for (int cf = 0; cf < 4; ++cf) {
        float rv1[4], rv2[4]; int ri1[4], ri2[4];
#pragma unroll
        for (int r = 0; r < 4; ++r) {
            const int c = (cw << 6) + (cf << 4) + (g << 2) + r;
            float dp = 0.f;
#pragma unroll
            for (int k = 0; k < 3; ++k)
                dp += x[(((b * C_ + c) * 3 + k) << 12) + nbase + t16] * acc[k][cf][r];
            dp *= 0.0625f;
            float v1 = dp, v2 = -__builtin_inff();
            int   i1 = nbase + t16, i2 = 0x7fffffff;
#pragma unroll
            for (int m = 1; m <= 8; m <<= 1) {
                float w1 = __shfl_xor(v1, m), w2 = __shfl_xor(v2, m);
                int   j1 = __shfl_xor(i1, m), j2 = __shfl_xor(i2, m);
                top2_merge(v1, i1, v2, i2, w1, j1, w2, j2);
            }
            rv1[r] = v1; ri1[r] = i1; rv2[r] = v2; ri2[r] = i2;
        }
        if (nw == 0 && t16 == 0) {
#pragma unroll
            for (int r = 0; r < 4; ++r) {
                const int c = (cw << 6) + (cf << 4) + (g << 2) + r;
                btmp[c] = make_float4(rv1[r], __int_as_float(ri1[r]),
                                      rv2[r], __int_as_float(ri2[r]));
            }
        }
        __syncthreads();
        if (nw == 1 && t16 == 0) {
#pragma unroll
            for (int r = 0; r < 4; ++r) {
                const int c = (cw << 6) + (cf << 4) + (g << 2) + r;
                float4 o = btmp[c];
                float v1 = rv1[r], v2 = rv2[r]; int i1 = ri1[r], i2 = ri2[r];
                top2_merge(v1, i1, v2, i2, o.x, __float_as_int(o.y),
                           o.z, __float_as_int(o.w));
                btop[(b * C_ + c) * 128 + nb] =
                    make_float4(v1, __int_as_float(i1), v2, __int_as_float(i2));
            }
        }
    }
}

// ---------- phase2: global top-2 merge, certify or exact-recompute, gather ----------
// grid: 4096 blocks x 64 threads (one wave per (b,c))
__global__ void phase2(const float* __restrict__ x, const float* __restrict__ W,
                       const float4* __restrict__ btop, float* __restrict__ out)
{
    const int bc = blockIdx.x;          // b*256 + c
    const int b = bc >> 8, c = bc & 255;
    const int lane = threadIdx.x;

    float4 e0 = btop[bc * 128 + lane];
    float4 e1 = btop[bc * 128 + 64 + lane];

    float v1 = e0.x; int i1 = __float_as_int(e0.y);
    float v2 = e0.z; int i2 = __float_as_int(e0.w);
    top2_merge(v1, i1, v2, i2, e1.x, __float_as_int(e1.y), e1.z, __float_as_int(e1.w));
#pragma unroll
    for (int m = 1; m <= 32; m <<= 1) {
        float w1 = __shfl_xor(v1, m), w2 = __shfl_xor(v2, m);
        int   j1 = __shfl_xor(i1, m), j2 = __shfl_xor(i2, m);
        top2_merge(v1, i1, v2, i2, w1, j1, w2, j2);
    }

    int winner = i1;
    if (!(v1 - v2 > TAU)) {
        // exact fp32 recompute of every 32-n window whose approx max is within TAU of v1
        float bv = -3.4e38f; int bi = 0x7fffffff;
#pragma unroll
        for (int t = 0; t < 2; ++t) {
            float4 e = t ? e1 : e0;
            bool flag = (e.x >= v1 - TAU);
            unsigned long long mask = __ballot(flag);
            while (mask) {
                int src = __builtin_ctzll(mask);
                mask &= mask - 1;
                int region = src + t * 64;
                int nb0 = region * 32;
                for (int ch = 0; ch < 4; ++ch) {
                    int nbase = nb0 + ch * 8;
                    float accv[8];
#pragma unroll
                    for (int m2 = 0; m2 < 8; ++m2) accv[m2] = 0.f;
                    float xc[3][8];
#pragma unroll
                    for (int k = 0; k < 3; ++k) {
                        const float* p = x + ((bc * 3 + k) << 12) + nbase;
#pragma unroll
                        for (int m2 = 0; m2 < 8; ++m2) xc[k][m2] = p[m2];
                    }
                    for (int q = 0; q < 4; ++q) {
                        int i = lane + (q << 6);
                        float wq = W[c * C_ + i];
#pragma unroll
                        for (int k = 0; k < 3; ++k) {
                            const float* p = x + (((b * C_ + i) * 3 + k) << 12) + nbase;
#pragma unroll
                            for (int m2 = 0; m2 < 8; ++m2)
                                accv[m2] += wq * p[m2] * xc[k][m2];
                        }
                    }
#pragma unroll
                    for (int m2 = 0; m2 < 8; ++m2) {
#pragma unroll
                        for (int mm = 1; mm <= 32; mm <<= 1)
                            accv[m2] += __shfl_xor(accv[m2], mm);
                        int n = nbase + m2;
                        if (accv[m2] > bv || (accv[m2] == bv && n < bi)) { bv = accv[m2]; bi = n; }
                    }
                }
            }
        }
        winner = bi;
    }

    if (lane < 3)
        out[bc * 3 + lane] = x[((bc * 3 + lane) << 12) + winner];
}

extern "C" void kernel_launch(void* const* d_in, const int* in_sizes, int n_in,
                              void* d_out, int out_size, void* d_ws, size_t ws_size,
                              hipStream_t stream) {
    const float* x = (const float*)d_in[0];
    const float* W = (const float*)d_in[1];
    float* out = (float*)d_out;

    _Float16* WfH  = (_Float16*)d_ws;                       // 128 KB
    _Float16* WfL  = (_Float16*)((char*)d_ws + 131072);     // 128 KB
    float4*   btop = (float4*)((char*)d_ws + 262144);       // 8 MB: [bc][128] (v1,i1,v2,i2)

    prep_w<<<32, 256, 0, stream>>>(W, WfH, WfL);
    vn_main<<<B_ * 128, 512, 0, stream>>>(x, WfH, WfL, btop);
    phase2<<<B_ * C_, 64, 0, stream>>>(x, W, btop, out);
}